// Round 2
// 540.616 us; speedup vs baseline: 1.0194x; 1.0194x over previous
//
#include <hip/hip_runtime.h>
#include <hip/hip_bf16.h>

#define N_NODES 8192
#define F_IN    128
#define F_OUT   64
#define GAT_ALPHA 0.2f
#define JSPLIT  16
#define COLS_PER_SPLIT (N_NODES / JSPLIT)   // 512
#define KC      64                           // columns per chunk
#define NCH     (COLS_PER_SPLIT / KC)        // 8
#define LSTR    72                           // padded LDS stride (bf16 elems, 144B rows)

typedef short  short8_t  __attribute__((ext_vector_type(8)));
typedef float  f32x4_t   __attribute__((ext_vector_type(4)));

static __device__ __forceinline__ unsigned int f32_to_bf16_bits(float x) {
    unsigned int u = __float_as_uint(x);
    return (u + 0x7fffu + ((u >> 16) & 1u)) >> 16;
}

// Kernel 1: Wh = h @ W (fp32); s1 = Wh@a1, s2 = Wh@a2.
// Wh stored bf16 in LOAD-ORDER tiles: wht[node/64][instr 0..7][lane 0..63][elem 0..7]
//   node c (in tile): kk=c>>5, q=(c>>3)&3, e=c&7;  feature f: t=f>>4, m=f&15
//   -> instr = kk*4+t, lane = q*16+m, elem = e.
// Every B-fragment load in k_attn becomes one contiguous 1KB wave read.
__global__ __launch_bounds__(256) void k_wh(
    const float* __restrict__ h, const float* __restrict__ W, const float* __restrict__ a,
    unsigned short* __restrict__ wht, float* __restrict__ s1, float* __restrict__ s2)
{
    __shared__ float Wl[F_IN][F_OUT];   // 32 KB
    int tid = threadIdx.x;
    #pragma unroll
    for (int i = 0; i < (F_IN * F_OUT) / 256; ++i) {
        int idx = tid + i * 256;
        Wl[idx >> 6][idx & 63] = W[idx];
    }
    __syncthreads();
    int wave = tid >> 6, lane = tid & 63;
    int row = blockIdx.x * 4 + wave;
    const float* hr = h + (size_t)row * F_IN;
    float acc = 0.f;
    #pragma unroll
    for (int k = 0; k < F_IN; k += 4) {
        float4 hv = *(const float4*)(hr + k);
        acc += hv.x * Wl[k + 0][lane];
        acc += hv.y * Wl[k + 1][lane];
        acc += hv.z * Wl[k + 2][lane];
        acc += hv.w * Wl[k + 3][lane];
    }
    int c  = row & 63, cb = row >> 6;
    int u  = ((c >> 5) << 2) + (lane >> 4);          // kk*4 + t
    int lp = (((c >> 3) & 3) << 4) + (lane & 15);    // q*16 + m
    wht[(size_t)cb * 4096 + u * 512 + lp * 8 + (c & 7)] =
        (unsigned short)f32_to_bf16_bits(acc);

    float p1 = acc * a[lane];
    float p2 = acc * a[F_OUT + lane];
    #pragma unroll
    for (int off = 32; off > 0; off >>= 1) {
        p1 += __shfl_down(p1, off);
        p2 += __shfl_down(p2, off);
    }
    if (lane == 0) { s1[row] = p1; s2[row] = p2; }
}

// Kernel 2: per-wave-independent, software-pipelined single pass.
// Wave: 16 rows x 512 cols, no __syncthreads.
// Coalesced load mapping: rg=lane>>4, sg=lane&15; instr t loads row row0+4t+rg,
// cols sg*4 -> each instr = 4 rows x 256B contiguous (16 merged lines vs 64 before).
// s2 collapses to one float4/lane. MFMA/LDS-read layout unchanged from verified kernel.
__global__ __launch_bounds__(256) void k_attn(
    const int* __restrict__ adj, const float* __restrict__ ef,
    const float* __restrict__ a,
    const float* __restrict__ s1, const float* __restrict__ s2,
    const unsigned short* __restrict__ wht,
    float* __restrict__ Osum, float* __restrict__ lsum)
{
    __shared__ unsigned short pl[4 * 2 * 16 * LSTR];   // 18432 B
    int tid  = threadIdx.x;
    int wave = tid >> 6, lane = tid & 63;
    int q = lane >> 4, m = lane & 15;   // MFMA-read roles
    int rg = q, sg = m;                 // load roles (same lane decomposition)
    int rowtile = blockIdx.x / JSPLIT;
    int split   = blockIdx.x % JSPLIT;
    int row0  = rowtile * 64 + wave * 16;
    int jbase = split * COLS_PER_SPLIT;

    float a_e = a[2 * F_OUT];
    float s1v[4];
    #pragma unroll
    for (int t = 0; t < 4; ++t) s1v[t] = s1[row0 + t * 4 + rg];

    const int*   adjp = adj + (size_t)(row0 + rg) * N_NODES + jbase + sg * 4;
    const float* efp  = ef  + (size_t)(row0 + rg) * N_NODES + jbase + sg * 4;
    const float* s2p  = s2 + jbase + sg * 4;
    const unsigned short* w3 = wht + (size_t)(split * NCH) * 4096 + lane * 8;
    unsigned short* plw = pl + wave * (2 * 16 * LSTR);

    f32x4_t acc0 = {0.f, 0.f, 0.f, 0.f};
    f32x4_t acc1 = acc0, acc2 = acc0, acc3 = acc0, accl = acc0;
    short8_t ones;
    #pragma unroll
    for (int i = 0; i < 8; ++i) ones[i] = (short)0x3F80;   // bf16 1.0

    const size_t RSTR = (size_t)4 * N_NODES;   // 4-row stride (elems)

    // prologue: prefetch chunk 0 (36 VGPRs of stream data in flight)
    int4   aj[4];
    float4 ev[4], sv;
    #pragma unroll
    for (int t = 0; t < 4; ++t) {
        aj[t] = *(const int4*)  (adjp + t * RSTR);
        ev[t] = *(const float4*)(efp  + t * RSTR);
    }
    sv = *(const float4*)s2p;

    #pragma unroll 2
    for (int ch = 0; ch < NCH; ++ch) {
        // 1) B-fragment loads: 8 contiguous 1KB wave reads (L2-hot) — OLDEST vmem
        const unsigned short* wt = w3 + (size_t)ch * 4096;
        short8_t b[8];
        #pragma unroll
        for (int u = 0; u < 8; ++u)
            b[u] = *(const short8_t*)(wt + u * 512);

        // 2) compute p from prefetched registers (frees aj/ev)
        uint2 pk[4];
        #pragma unroll
        for (int t = 0; t < 4; ++t) {
            float sb = s1v[t];
            float e0 = fmaf(ev[t].x, a_e, sb + sv.x); e0 = fmaxf(e0, GAT_ALPHA * e0);
            float e1 = fmaf(ev[t].y, a_e, sb + sv.y); e1 = fmaxf(e1, GAT_ALPHA * e1);
            float e2 = fmaf(ev[t].z, a_e, sb + sv.z); e2 = fmaxf(e2, GAT_ALPHA * e2);
            float e3 = fmaf(ev[t].w, a_e, sb + sv.w); e3 = fmaxf(e3, GAT_ALPHA * e3);
            float p0 = (aj[t].x > 0) ? __expf(e0) : 0.f;
            float p1 = (aj[t].y > 0) ? __expf(e1) : 0.f;
            float p2 = (aj[t].z > 0) ? __expf(e2) : 0.f;
            float p3 = (aj[t].w > 0) ? __expf(e3) : 0.f;
            pk[t].x = f32_to_bf16_bits(p0) | (f32_to_bf16_bits(p1) << 16);
            pk[t].y = f32_to_bf16_bits(p2) | (f32_to_bf16_bits(p3) << 16);
        }

        // 3) prefetch next chunk — YOUNGEST vmem; stays outstanding through MFMA
        if (ch + 1 < NCH) {
            adjp += KC; efp += KC; s2p += KC;
            #pragma unroll
            for (int t = 0; t < 4; ++t) {
                aj[t] = *(const int4*)  (adjp + t * RSTR);
                ev[t] = *(const float4*)(efp  + t * RSTR);
            }
            sv = *(const float4*)s2p;
        }

        // 4) p-tile to wave-private LDS (double-buffered; wave-local => no barrier)
        unsigned short* pb = plw + (ch & 1) * (16 * LSTR);
        #pragma unroll
        for (int t = 0; t < 4; ++t)
            *(uint2*)&pb[(t * 4 + rg) * LSTR + sg * 4] = pk[t];

        // 5) MFMA phase: A-frags from LDS, consume B-loads (prefetch stays alive)
        const unsigned short* pr = pb + m * LSTR;
        #pragma unroll
        for (int kk = 0; kk < 2; ++kk) {
            short8_t af = *(const short8_t*)&pr[kk * 32 + q * 8];
            acc0 = __builtin_amdgcn_mfma_f32_16x16x32_bf16(af, b[kk * 4 + 0], acc0, 0, 0, 0);
            acc1 = __builtin_amdgcn_mfma_f32_16x16x32_bf16(af, b[kk * 4 + 1], acc1, 0, 0, 0);
            acc2 = __builtin_amdgcn_mfma_f32_16x16x32_bf16(af, b[kk * 4 + 2], acc2, 0, 0, 0);
            acc3 = __builtin_amdgcn_mfma_f32_16x16x32_bf16(af, b[kk * 4 + 3], acc3, 0, 0, 0);
            accl = __builtin_amdgcn_mfma_f32_16x16x32_bf16(af, ones, accl, 0, 0, 0);
        }
    }

    #pragma unroll
    for (int rr = 0; rr < 4; ++rr) {
        int orow = row0 + q * 4 + rr;
        float* op = Osum + (size_t)orow * F_OUT + m;
        atomicAdd(op +  0, acc0[rr]);
        atomicAdd(op + 16, acc1[rr]);
        atomicAdd(op + 32, acc2[rr]);
        atomicAdd(op + 48, acc3[rr]);
    }
    if (m == 0) {
        #pragma unroll
        for (int rr = 0; rr < 4; ++rr)
            atomicAdd(&lsum[row0 + q * 4 + rr], accl[rr]);
    }
}

// Kernel 3: normalize + ELU
__global__ __launch_bounds__(256) void k_out(
    const float* __restrict__ Osum, const float* __restrict__ lsum, float* __restrict__ out)
{
    int i = blockIdx.x * 256 + threadIdx.x;
    float v = Osum[i] / lsum[i >> 6];
    out[i] = (v > 0.f) ? v : (__expf(v) - 1.f);
}

extern "C" void kernel_launch(void* const* d_in, const int* in_sizes, int n_in,
                              void* d_out, int out_size, void* d_ws, size_t ws_size,
                              hipStream_t stream)
{
    const float* h   = (const float*)d_in[0];
    const int*   adj = (const int*)d_in[1];
    const float* ef  = (const float*)d_in[2];
    const float* W   = (const float*)d_in[3];
    const float* a   = (const float*)d_in[4];
    float* out = (float*)d_out;

    char* ws = (char*)d_ws;
    unsigned short* wht = (unsigned short*)ws;                       // 1 MB
    float* s1   = (float*)(ws + (size_t)F_OUT * N_NODES * 2);        // 32 KB
    float* s2   = s1 + N_NODES;                                      // 32 KB
    float* Osum = s2 + N_NODES;                                      // 2 MB
    float* lsum = Osum + (size_t)N_NODES * F_OUT;                    // 32 KB

    hipMemsetAsync(Osum, 0, ((size_t)N_NODES * F_OUT + N_NODES) * sizeof(float), stream);

    k_wh  <<<N_NODES / 4, 256, 0, stream>>>(h, W, a, wht, s1, s2);
    k_attn<<<(N_NODES / 64) * JSPLIT, 256, 0, stream>>>(adj, ef, a, s1, s2, wht, Osum, lsum);
    k_out <<<(N_NODES * F_OUT) / 256, 256, 0, stream>>>(Osum, lsum, out);
}